// Round 1
// baseline (4005.292 us; speedup 1.0000x reference)
//
#include <hip/hip_runtime.h>

// Problem constants (fixed by the reference)
#define P 8
#define T 200
#define C 20
#define F 512
#define NQ 1024
#define MAXN 40                    // max samples per class we support (true ~10±4)
#define MMAX (T + MAXN)            // 240
#define PACK ((MMAX*(MMAX+1))/2)   // 28920 packed lower-tri floats
#define QL (NQ*C)                  // 20480 logits

// Workspace layout (float offsets)
enum : int {
  OFF_G    = 0,                       // P*T*T      = 320000
  OFF_SQ   = OFF_G   + P*T*T,         // P*T*NQ     = 1638400
  OFF_G1   = OFF_SQ  + P*T*NQ,        // P*T
  OFF_GG   = OFF_G1  + P*T,           // P
  OFF_GM   = OFF_GG  + P,             // P*T*C
  OFF_GMC  = OFF_GM  + P*T*C,         // P*C
  OFF_MM   = OFF_GMC + P*C,           // P*C
  OFF_GQ   = OFF_MM  + P*C,           // P*NQ
  OFF_QN   = OFF_GQ  + P*NQ,          // P*NQ
  OFF_MQ   = OFF_QN  + P*NQ,          // P*C*NQ
  OFF_W    = OFF_MQ  + P*C*NQ,        // P*C*PACK   = 4627200
  OFF_QUAD = OFF_W   + P*C*PACK,      // P*NQ*C
  OFF_CLSF = OFF_QUAD+ P*NQ*C,        // C*8 scalars
  OFF_INT  = OFF_CLSF+ C*8            // int region: counts[C], idx[C*MAXN]
};

__device__ __forceinline__ int offr(int i){ return (i*(i+1))>>1; }

// ---------------- setup: counts, per-class index lists, scalars ----------------
__global__ void k_setup(const int* lab, float* ws){
  int c = threadIdx.x;
  if (c >= C) return;
  int* wsI = (int*)(ws + OFF_INT);
  int n = 0;
  for (int t = 0; t < T; ++t){
    if (lab[t] == c){ if (n < MAXN) wsI[C + c*MAXN + n] = t; ++n; }
  }
  if (n > MAXN) n = MAXN;
  wsI[c] = n;
  float nf    = (float)n;
  float nsafe = fmaxf(nf, 1.0f);
  float dn    = fmaxf(nf - 1.0f, 1.0f);
  float lam   = nsafe / (nsafe + 1.0f);
  float sv    = (1.0f - lam) / (float)(T - 1);
  float av    = lam / dn;
  float* cf = ws + OFF_CLSF + c*8;
  cf[0] = nsafe; cf[1] = dn; cf[2] = lam; cf[3] = sv; cf[4] = av;
  cf[5] = sqrtf(sv); cf[6] = sqrtf(av); cf[7] = 0.0f;
}

// ---------------- G = X X^T per p (200x200) ----------------
__global__ __launch_bounds__(256) void k_gram(const float* X, float* ws){
  __shared__ float Xi[32][33];
  __shared__ float Xj[32][33];
  const int p = blockIdx.z, i0 = blockIdx.y*32, j0 = blockIdx.x*32;
  const int tx = threadIdx.x, ty = threadIdx.y;
  const int tid = ty*16 + tx;
  const float* Xp = X + (size_t)p*T*F;
  float acc[2][2] = {{0.f,0.f},{0.f,0.f}};
  for (int kb = 0; kb < F; kb += 32){
    for (int e = tid; e < 32*32; e += 256){
      int r = e >> 5, kk = e & 31;
      Xi[r][kk] = (i0+r < T) ? Xp[(i0+r)*F + kb+kk] : 0.f;
      Xj[r][kk] = (j0+r < T) ? Xp[(j0+r)*F + kb+kk] : 0.f;
    }
    __syncthreads();
    for (int kk = 0; kk < 32; ++kk){
      float a0 = Xi[2*ty][kk],   a1 = Xi[2*ty+1][kk];
      float b0 = Xj[2*tx][kk],   b1 = Xj[2*tx+1][kk];
      acc[0][0] += a0*b0; acc[0][1] += a0*b1;
      acc[1][0] += a1*b0; acc[1][1] += a1*b1;
    }
    __syncthreads();
  }
  float* Gp = ws + OFF_G + (size_t)p*T*T;
  for (int a = 0; a < 2; ++a)
    for (int b = 0; b < 2; ++b){
      int i = i0 + 2*ty + a, j = j0 + 2*tx + b;
      if (i < T && j < T) Gp[i*T + j] = acc[a][b];
    }
}

// ---------------- per-p stats: g1, gg, Gm, gmc, mm ----------------
__global__ __launch_bounds__(256) void k_pstats(float* ws){
  const int p = blockIdx.x, tid = threadIdx.x;
  const int* wsI = (const int*)(ws + OFF_INT);
  const float* Gp = ws + OFF_G + (size_t)p*T*T;
  float* g1 = ws + OFF_G1 + p*T;
  for (int t = tid; t < T; t += 256){
    float s = 0.f;
    for (int u = 0; u < T; ++u) s += Gp[t*T + u];
    g1[t] = s * (1.0f/T);
  }
  __syncthreads();
  if (tid == 0){
    float s = 0.f;
    for (int t = 0; t < T; ++t) s += g1[t];
    ws[OFF_GG + p] = s * (1.0f/T);
  }
  float* Gm = ws + OFF_GM + (size_t)p*T*C;
  for (int t = tid; t < T; t += 256){
    for (int c = 0; c < C; ++c){
      int n = wsI[c];
      const int* idxc = wsI + C + c*MAXN;
      float s = 0.f;
      for (int j = 0; j < n; ++j) s += Gp[t*T + idxc[j]];
      Gm[t*C + c] = s / ws[OFF_CLSF + c*8];
    }
  }
  __syncthreads();
  if (tid < C){
    int c = tid, n = wsI[c];
    const int* idxc = wsI + C + c*MAXN;
    float s = 0.f;
    for (int t = 0; t < T; ++t) s += Gm[t*C + c];
    ws[OFF_GMC + p*C + c] = s * (1.0f/T);
    float s2 = 0.f;
    for (int j = 0; j < n; ++j) s2 += Gm[idxc[j]*C + c];
    ws[OFF_MM + p*C + c] = s2 / ws[OFF_CLSF + c*8];
  }
}

// ---------------- class means -> output part 2 ----------------
__global__ __launch_bounds__(256) void k_means(const float* X, const float* ws, float* out){
  const int blk = blockIdx.x, p = blk / C, c = blk % C;
  const int* wsI = (const int*)(ws + OFF_INT);
  const int n = wsI[c];
  const int* idxc = wsI + C + c*MAXN;
  const float nf = ws[OFF_CLSF + c*8];
  const float* Xp = X + (size_t)p*T*F;
  float* o = out + QL + (size_t)(p*C + c)*F;
  for (int f = threadIdx.x; f < F; f += 256){
    float s = 0.f;
    for (int j = 0; j < n; ++j) s += Xp[idxc[j]*F + f];
    o[f] = s / nf;
  }
}

// ---------------- SQ = X Q^T per p (200x1024) ----------------
__global__ __launch_bounds__(256) void k_sq(const float* X, const float* Qf, float* ws){
  __shared__ float Xt[32][33];
  __shared__ float Qt[64][33];
  const int p = blockIdx.z, t0 = blockIdx.x*32, q0 = blockIdx.y*64;
  const int tx = threadIdx.x, ty = threadIdx.y;
  const int tid = ty*16 + tx;
  const float* Xp = X  + (size_t)p*T*F;
  const float* Qp = Qf + (size_t)p*NQ*F;
  float acc[2][4] = {};
  for (int kb = 0; kb < F; kb += 32){
    for (int e = tid; e < 32*32; e += 256){
      int r = e >> 5, kk = e & 31;
      Xt[r][kk] = (t0+r < T) ? Xp[(t0+r)*F + kb+kk] : 0.f;
    }
    for (int e = tid; e < 64*32; e += 256){
      int r = e >> 5, kk = e & 31;
      Qt[r][kk] = Qp[(q0+r)*F + kb+kk];
    }
    __syncthreads();
    for (int kk = 0; kk < 32; ++kk){
      float a0 = Xt[2*ty][kk], a1 = Xt[2*ty+1][kk];
      float b0 = Qt[4*tx][kk], b1 = Qt[4*tx+1][kk], b2 = Qt[4*tx+2][kk], b3 = Qt[4*tx+3][kk];
      acc[0][0] += a0*b0; acc[0][1] += a0*b1; acc[0][2] += a0*b2; acc[0][3] += a0*b3;
      acc[1][0] += a1*b0; acc[1][1] += a1*b1; acc[1][2] += a1*b2; acc[1][3] += a1*b3;
    }
    __syncthreads();
  }
  float* SQp = ws + OFF_SQ + (size_t)p*T*NQ;
  for (int a = 0; a < 2; ++a){
    int t = t0 + 2*ty + a;
    if (t < T)
      for (int b = 0; b < 4; ++b)
        SQp[t*NQ + q0 + 4*tx + b] = acc[a][b];
  }
}

// ---------------- per-q stats: gq, mq, qn ----------------
__global__ __launch_bounds__(256) void k_qstats(const float* Qf, float* ws){
  const int p = blockIdx.y;
  const int q = blockIdx.x*256 + threadIdx.x;
  const int* wsI = (const int*)(ws + OFF_INT);
  const float* SQp = ws + OFF_SQ + (size_t)p*T*NQ;
  float s = 0.f;
  for (int t = 0; t < T; ++t) s += SQp[t*NQ + q];
  ws[OFF_GQ + p*NQ + q] = s * (1.0f/T);
  for (int c = 0; c < C; ++c){
    int n = wsI[c];
    const int* idxc = wsI + C + c*MAXN;
    float sc = 0.f;
    for (int j = 0; j < n; ++j) sc += SQp[idxc[j]*NQ + q];
    ws[OFF_MQ + ((size_t)(p*C + c))*NQ + q] = sc / ws[OFF_CLSF + c*8];
  }
  const float* qr = Qf + ((size_t)p*NQ + q)*F;
  float qs = 0.f;
  for (int f = 0; f < F; ++f){ float v = qr[f]; qs += v*v; }
  ws[OFF_QN + p*NQ + q] = qs;
}

// ---------------- build M, packed-LDS Cholesky, in-place W=L^-1, store W ----------------
__global__ __launch_bounds__(256) void k_factor(float* ws){
  __shared__ float Lp[PACK];      // packed lower triangle, 115.7 KB
  __shared__ float colbuf[MMAX];
  const int blk = blockIdx.x, p = blk / C, c = blk % C;
  const int tid = threadIdx.x;
  const int* wsI = (const int*)(ws + OFF_INT);
  const int n = wsI[c];
  const int m = T + n;
  const int* idxc = wsI + C + c*MAXN;
  const float* cf = ws + OFF_CLSF + c*8;
  const float sv = cf[3], av = cf[4], sqsa = cf[5]*cf[6];
  const float* Gp  = ws + OFF_G  + (size_t)p*T*T;
  const float* g1p = ws + OFF_G1 + p*T;
  const float  ggv = ws[OFF_GG + p];
  const float* Gmp = ws + OFF_GM + (size_t)p*T*C;
  const float gmcv = ws[OFF_GMC + p*C + c];
  const float mmv  = ws[OFF_MM  + p*C + c];

  // ---- build M (lower triangle) ----
  for (int i = 0; i < m; ++i){
    int o = offr(i);
    if (i < T){
      float gi = g1p[i];
      for (int j = tid; j <= i; j += 256){
        float v = sv*(Gp[i*T + j] - gi - g1p[j] + ggv);
        if (j == i) v += 1.0f;
        Lp[o + j] = v;
      }
    } else {
      int ua = idxc[i - T];
      float gmua = Gmp[ua*C + c];
      float g1ua = g1p[ua];
      for (int j = tid; j <= i; j += 256){
        float v;
        if (j < T){
          v = sqsa*(Gp[ua*T + j] - Gmp[j*C + c] - g1ua + gmcv);
        } else {
          int ub = idxc[j - T];
          v = av*(Gp[ua*T + ub] - gmua - Gmp[ub*C + c] + mmv);
          if (j == i) v += 1.0f;
        }
        Lp[o + j] = v;
      }
    }
  }
  __syncthreads();

  // ---- Cholesky (right-looking, no pivoting: pivots >= 1 since M = I + PSD) ----
  for (int k = 0; k < m; ++k){
    const int ok = offr(k);
    float dkk = Lp[ok + k];
    __syncthreads();                       // everyone has read dkk before diag write
    float inv = 1.0f / sqrtf(dkk);
    for (int i = k + tid; i < m; i += 256) Lp[offr(i) + k] *= inv;  // tid0 sets diag=sqrt
    __syncthreads();
    for (int i = k + 1 + tid; i < m; i += 256){
      int oi = offr(i);
      float cik = Lp[oi + k];
      for (int j = k + 1; j <= i; ++j) Lp[oi + j] -= cik * Lp[offr(j) + k];
    }
    __syncthreads();
  }

  // ---- in-place triangular inversion: columns descending ----
  for (int j = m - 1; j >= 0; --j){
    for (int k = j + tid; k < m; k += 256) colbuf[k] = Lp[offr(k) + j];
    __syncthreads();
    float invd = 1.0f / colbuf[j];
    for (int i = j + tid; i < m; i += 256){
      if (i == j){
        Lp[offr(j) + j] = invd;
      } else {
        int oi = offr(i);
        float acc = 0.f;
        for (int k = j + 1; k <= i; ++k) acc += Lp[oi + k] * colbuf[k];
        Lp[oi + j] = -invd * acc;
      }
    }
    __syncthreads();
  }

  // ---- store W packed ----
  float* Wg = ws + OFF_W + (size_t)blk * PACK;
  const int tot = offr(m - 1) + m;  // m*(m+1)/2
  for (int e = tid; e < tot; e += 256) Wg[e] = Lp[e];
}

// ---------------- apply: quad = ||d||^2 - ||W (Vd)||^2 ----------------
__global__ __launch_bounds__(256) void k_apply(float* ws){
  __shared__ float E[MMAX][64];   // Vd for 64 queries, 61.4 KB
  __shared__ float red[4][64];
  const int p = blockIdx.z, c = blockIdx.y, q0 = blockIdx.x*64;
  const int tid = threadIdx.x;
  const int* wsI = (const int*)(ws + OFF_INT);
  const int n = wsI[c], m = T + n;
  const int* idxc = wsI + C + c*MAXN;
  const float* cf = ws + OFF_CLSF + c*8;
  const float sqs = cf[5], sqa = cf[6];
  const float gmcv = ws[OFF_GMC + p*C + c];
  const float mmv  = ws[OFF_MM  + p*C + c];
  const float* Gmp = ws + OFF_GM + (size_t)p*T*C;
  const float* SQp = ws + OFF_SQ + (size_t)p*T*NQ;
  const float* gqp = ws + OFF_GQ + p*NQ + q0;
  const float* qnp = ws + OFF_QN + p*NQ + q0;
  const float* mqp = ws + OFF_MQ + ((size_t)(p*C + c))*NQ + q0;

  for (int lin = tid; lin < m*64; lin += 256){
    int j = lin >> 6, ql = lin & 63;
    float v;
    if (j < T){
      v = sqs*(Gmp[j*C + c] - SQp[j*NQ + q0 + ql] - gmcv + gqp[ql]);
    } else {
      int u = idxc[j - T];
      v = sqa*(Gmp[u*C + c] - SQp[u*NQ + q0 + ql] - mmv + mqp[ql]);
    }
    E[j][ql] = v;
  }
  __syncthreads();

  const int rg = tid >> 6, ql = tid & 63;
  const float* Wb = ws + OFF_W + (size_t)(p*C + c)*PACK;
  float ss = 0.f;
  for (int k = rg; k < m; k += 4){
    const float* wr = Wb + offr(k);
    float y = 0.f;
    for (int j = 0; j <= k; ++j) y += wr[j] * E[j][ql];
    ss += y*y;
  }
  red[rg][ql] = ss;
  __syncthreads();
  if (rg == 0){
    float tot = red[0][ql] + red[1][ql] + red[2][ql] + red[3][ql];
    float quad = mmv - 2.f*mqp[ql] + qnp[ql] - tot;
    ws[OFF_QUAD + ((size_t)p*NQ + q0 + ql)*C + c] = quad;
  }
}

// ---------------- logits: mean over p ----------------
__global__ void k_logits(const float* ws, float* out){
  int lin = blockIdx.x*256 + threadIdx.x;
  if (lin < QL){
    float s = 0.f;
    for (int p = 0; p < P; ++p) s += ws[OFF_QUAD + (size_t)p*NQ*C + lin];
    out[lin] = -s * (1.0f/P);
  }
}

extern "C" void kernel_launch(void* const* d_in, const int* in_sizes, int n_in,
                              void* d_out, int out_size, void* d_ws, size_t ws_size,
                              hipStream_t stream){
  const float* X   = (const float*)d_in[0];
  const int*   lab = (const int*)d_in[1];
  const float* Qf  = (const float*)d_in[2];
  float* out = (float*)d_out;
  float* ws  = (float*)d_ws;

  k_setup <<<1, 64, 0, stream>>>(lab, ws);
  k_gram  <<<dim3(7,7,P),  dim3(16,16), 0, stream>>>(X, ws);
  k_pstats<<<P, 256, 0, stream>>>(ws);
  k_means <<<P*C, 256, 0, stream>>>(X, ws, out);
  k_sq    <<<dim3(7,16,P), dim3(16,16), 0, stream>>>(X, Qf, ws);
  k_qstats<<<dim3(4,P), 256, 0, stream>>>(Qf, ws);
  k_factor<<<P*C, 256, 0, stream>>>(ws);
  k_apply <<<dim3(16,C,P), 256, 0, stream>>>(ws);
  k_logits<<<QL/256, 256, 0, stream>>>(ws, out);
}

// Round 2
// 1519.286 us; speedup vs baseline: 2.6363x; 2.6363x over previous
//
#include <hip/hip_runtime.h>

// Problem constants (fixed by the reference)
#define P 8
#define T 200
#define C 20
#define F 512
#define NQ 1024
#define MAXN 40                    // max samples per class we support (true ~10±4)
#define MMAX (T + MAXN)            // 240
#define PACK ((MMAX*(MMAX+1))/2)   // 28920 packed lower-tri floats
#define QL (NQ*C)                  // 20480 logits
#define NB 16                      // Cholesky panel width

// Workspace layout (float offsets)
enum : int {
  OFF_G    = 0,                       // P*T*T      = 320000
  OFF_SQ   = OFF_G   + P*T*T,         // P*T*NQ     = 1638400
  OFF_G1   = OFF_SQ  + P*T*NQ,        // P*T
  OFF_GG   = OFF_G1  + P*T,           // P
  OFF_GM   = OFF_GG  + P,             // P*T*C
  OFF_GMC  = OFF_GM  + P*T*C,         // P*C
  OFF_MM   = OFF_GMC + P*C,           // P*C
  OFF_GQ   = OFF_MM  + P*C,           // P*NQ
  OFF_QN   = OFF_GQ  + P*NQ,          // P*NQ
  OFF_MQ   = OFF_QN  + P*NQ,          // P*C*NQ
  OFF_W    = OFF_MQ  + P*C*NQ,        // P*C*PACK : packed L, diag 16x16 blocks INVERTED
  OFF_QUAD = OFF_W   + P*C*PACK,      // P*NQ*C
  OFF_CLSF = OFF_QUAD+ P*NQ*C,        // C*8 scalars
  OFF_INT  = OFF_CLSF+ C*8            // int region: counts[C], idx[C*MAXN]
};

__device__ __forceinline__ int offr(int i){ return (i*(i+1))>>1; }

// flat packed index e -> row i (lower triangle, row-packed)
__device__ __forceinline__ int row_of(int e){
  int i = (int)((sqrtf(8.f*(float)e + 1.f) - 1.f) * 0.5f);
  while (offr(i+1) <= e) ++i;
  while (offr(i) > e) --i;
  return i;
}

// ---------------- setup: counts, per-class index lists, scalars ----------------
__global__ void k_setup(const int* lab, float* ws){
  int c = threadIdx.x;
  if (c >= C) return;
  int* wsI = (int*)(ws + OFF_INT);
  int n = 0;
  for (int t = 0; t < T; ++t){
    if (lab[t] == c){ if (n < MAXN) wsI[C + c*MAXN + n] = t; ++n; }
  }
  if (n > MAXN) n = MAXN;
  wsI[c] = n;
  float nf    = (float)n;
  float nsafe = fmaxf(nf, 1.0f);
  float dn    = fmaxf(nf - 1.0f, 1.0f);
  float lam   = nsafe / (nsafe + 1.0f);
  float sv    = (1.0f - lam) / (float)(T - 1);
  float av    = lam / dn;
  float* cf = ws + OFF_CLSF + c*8;
  cf[0] = nsafe; cf[1] = dn; cf[2] = lam; cf[3] = sv; cf[4] = av;
  cf[5] = sqrtf(sv); cf[6] = sqrtf(av); cf[7] = 0.0f;
}

// ---------------- G = X X^T per p (200x200) ----------------
__global__ __launch_bounds__(256) void k_gram(const float* X, float* ws){
  __shared__ float Xi[32][33];
  __shared__ float Xj[32][33];
  const int p = blockIdx.z, i0 = blockIdx.y*32, j0 = blockIdx.x*32;
  const int tx = threadIdx.x, ty = threadIdx.y;
  const int tid = ty*16 + tx;
  const float* Xp = X + (size_t)p*T*F;
  float acc[2][2] = {{0.f,0.f},{0.f,0.f}};
  for (int kb = 0; kb < F; kb += 32){
    for (int e = tid; e < 32*32; e += 256){
      int r = e >> 5, kk = e & 31;
      Xi[r][kk] = (i0+r < T) ? Xp[(i0+r)*F + kb+kk] : 0.f;
      Xj[r][kk] = (j0+r < T) ? Xp[(j0+r)*F + kb+kk] : 0.f;
    }
    __syncthreads();
    for (int kk = 0; kk < 32; ++kk){
      float a0 = Xi[2*ty][kk],   a1 = Xi[2*ty+1][kk];
      float b0 = Xj[2*tx][kk],   b1 = Xj[2*tx+1][kk];
      acc[0][0] += a0*b0; acc[0][1] += a0*b1;
      acc[1][0] += a1*b0; acc[1][1] += a1*b1;
    }
    __syncthreads();
  }
  float* Gp = ws + OFF_G + (size_t)p*T*T;
  for (int a = 0; a < 2; ++a)
    for (int b = 0; b < 2; ++b){
      int i = i0 + 2*ty + a, j = j0 + 2*tx + b;
      if (i < T && j < T) Gp[i*T + j] = acc[a][b];
    }
}

// ---------------- per-p stats: g1, gg, Gm, gmc, mm ----------------
__global__ __launch_bounds__(256) void k_pstats(float* ws){
  const int p = blockIdx.x, tid = threadIdx.x;
  const int* wsI = (const int*)(ws + OFF_INT);
  const float* Gp = ws + OFF_G + (size_t)p*T*T;
  float* g1 = ws + OFF_G1 + p*T;
  for (int t = tid; t < T; t += 256){
    float s = 0.f;
    for (int u = 0; u < T; ++u) s += Gp[t*T + u];
    g1[t] = s * (1.0f/T);
  }
  __syncthreads();
  if (tid == 0){
    float s = 0.f;
    for (int t = 0; t < T; ++t) s += g1[t];
    ws[OFF_GG + p] = s * (1.0f/T);
  }
  float* Gm = ws + OFF_GM + (size_t)p*T*C;
  for (int t = tid; t < T; t += 256){
    for (int c = 0; c < C; ++c){
      int n = wsI[c];
      const int* idxc = wsI + C + c*MAXN;
      float s = 0.f;
      for (int j = 0; j < n; ++j) s += Gp[t*T + idxc[j]];
      Gm[t*C + c] = s / ws[OFF_CLSF + c*8];
    }
  }
  __syncthreads();
  if (tid < C){
    int c = tid, n = wsI[c];
    const int* idxc = wsI + C + c*MAXN;
    float s = 0.f;
    for (int t = 0; t < T; ++t) s += Gm[t*C + c];
    ws[OFF_GMC + p*C + c] = s * (1.0f/T);
    float s2 = 0.f;
    for (int j = 0; j < n; ++j) s2 += Gm[idxc[j]*C + c];
    ws[OFF_MM + p*C + c] = s2 / ws[OFF_CLSF + c*8];
  }
}

// ---------------- class means -> output part 2 ----------------
__global__ __launch_bounds__(256) void k_means(const float* X, const float* ws, float* out){
  const int blk = blockIdx.x, p = blk / C, c = blk % C;
  const int* wsI = (const int*)(ws + OFF_INT);
  const int n = wsI[c];
  const int* idxc = wsI + C + c*MAXN;
  const float nf = ws[OFF_CLSF + c*8];
  const float* Xp = X + (size_t)p*T*F;
  float* o = out + QL + (size_t)(p*C + c)*F;
  for (int f = threadIdx.x; f < F; f += 256){
    float s = 0.f;
    for (int j = 0; j < n; ++j) s += Xp[idxc[j]*F + f];
    o[f] = s / nf;
  }
}

// ---------------- SQ = X Q^T per p (200x1024) ----------------
__global__ __launch_bounds__(256) void k_sq(const float* X, const float* Qf, float* ws){
  __shared__ float Xt[32][33];
  __shared__ float Qt[64][33];
  const int p = blockIdx.z, t0 = blockIdx.x*32, q0 = blockIdx.y*64;
  const int tx = threadIdx.x, ty = threadIdx.y;
  const int tid = ty*16 + tx;
  const float* Xp = X  + (size_t)p*T*F;
  const float* Qp = Qf + (size_t)p*NQ*F;
  float acc[2][4] = {};
  for (int kb = 0; kb < F; kb += 32){
    for (int e = tid; e < 32*32; e += 256){
      int r = e >> 5, kk = e & 31;
      Xt[r][kk] = (t0+r < T) ? Xp[(t0+r)*F + kb+kk] : 0.f;
    }
    for (int e = tid; e < 64*32; e += 256){
      int r = e >> 5, kk = e & 31;
      Qt[r][kk] = Qp[(q0+r)*F + kb+kk];
    }
    __syncthreads();
    for (int kk = 0; kk < 32; ++kk){
      float a0 = Xt[2*ty][kk], a1 = Xt[2*ty+1][kk];
      float b0 = Qt[4*tx][kk], b1 = Qt[4*tx+1][kk], b2 = Qt[4*tx+2][kk], b3 = Qt[4*tx+3][kk];
      acc[0][0] += a0*b0; acc[0][1] += a0*b1; acc[0][2] += a0*b2; acc[0][3] += a0*b3;
      acc[1][0] += a1*b0; acc[1][1] += a1*b1; acc[1][2] += a1*b2; acc[1][3] += a1*b3;
    }
    __syncthreads();
  }
  float* SQp = ws + OFF_SQ + (size_t)p*T*NQ;
  for (int a = 0; a < 2; ++a){
    int t = t0 + 2*ty + a;
    if (t < T)
      for (int b = 0; b < 4; ++b)
        SQp[t*NQ + q0 + 4*tx + b] = acc[a][b];
  }
}

// ---------------- per-q stats: gq, mq, qn ----------------
__global__ __launch_bounds__(256) void k_qstats(const float* Qf, float* ws){
  const int p = blockIdx.y;
  const int q = blockIdx.x*256 + threadIdx.x;
  const int* wsI = (const int*)(ws + OFF_INT);
  const float* SQp = ws + OFF_SQ + (size_t)p*T*NQ;
  float s = 0.f;
  for (int t = 0; t < T; ++t) s += SQp[t*NQ + q];
  ws[OFF_GQ + p*NQ + q] = s * (1.0f/T);
  for (int c = 0; c < C; ++c){
    int n = wsI[c];
    const int* idxc = wsI + C + c*MAXN;
    float sc = 0.f;
    for (int j = 0; j < n; ++j) sc += SQp[idxc[j]*NQ + q];
    ws[OFF_MQ + ((size_t)(p*C + c))*NQ + q] = sc / ws[OFF_CLSF + c*8];
  }
  const float* qr = Qf + ((size_t)p*NQ + q)*F;
  float qs = 0.f;
  for (int f = 0; f < F; ++f){ float v = qr[f]; qs += v*v; }
  ws[OFF_QN + p*NQ + q] = qs;
}

// ---------------- build M, BLOCKED packed-LDS Cholesky; invert 16x16 diag blocks
//                  in place; store packed L (diag blocks = their inverses) ----------------
__global__ __launch_bounds__(256) void k_factor(float* ws){
  __shared__ float Lp[PACK];            // packed lower triangle, 115.7 KB
  __shared__ float Pn[MMAX+4][NB+1];    // padded panel buffer, 16.6 KB
  const int blk = blockIdx.x, p = blk / C, c = blk % C;
  const int tid = threadIdx.x;
  const int* wsI = (const int*)(ws + OFF_INT);
  const int n = wsI[c];
  const int m = T + n;
  const int* idxc = wsI + C + c*MAXN;
  const float* cf = ws + OFF_CLSF + c*8;
  const float sv = cf[3], av = cf[4], sqsa = cf[5]*cf[6];
  const float* Gp  = ws + OFF_G  + (size_t)p*T*T;
  const float* g1p = ws + OFF_G1 + p*T;
  const float  ggv = ws[OFF_GG + p];
  const float* Gmp = ws + OFF_GM + (size_t)p*T*C;
  const float gmcv = ws[OFF_GMC + p*C + c];
  const float mmv  = ws[OFF_MM  + p*C + c];
  const int tot = (m*(m+1)) >> 1;

  // ---- build M packed, fully parallel over the flat triangle ----
  for (int e = tid; e < tot; e += 256){
    int i = row_of(e);
    int j = e - offr(i);
    float v;
    if (i < T){
      v = sv*(Gp[i*T + j] - g1p[i] - g1p[j] + ggv);
      if (j == i) v += 1.0f;
    } else {
      int ua = idxc[i - T];
      if (j < T){
        v = sqsa*(Gp[ua*T + j] - Gmp[j*C + c] - g1p[ua] + gmcv);
      } else {
        int ub = idxc[j - T];
        v = av*(Gp[ua*T + ub] - Gmp[ua*C + c] - Gmp[ub*C + c] + mmv);
        if (j == i) v += 1.0f;
      }
    }
    Lp[e] = v;
  }
  __syncthreads();

  // ---- blocked right-looking Cholesky ----
  for (int k0 = 0; k0 < m; k0 += NB){
    const int kb = min(NB, m - k0);
    const int rows = m - k0;
    const int rowsP = (rows + 3) & ~3;   // zero-fill so 4x4 tiles read clean data
    // stage panel (rows k0..m-1, cols k0..k0+kb-1) into padded buffer
    for (int e = tid; e < rowsP*NB; e += 256){
      int r = e >> 4, cl = e & 15;
      float v = 0.f;
      if (r < rows && cl < kb && (r >= NB || cl <= r)) v = Lp[offr(k0+r) + k0 + cl];
      Pn[r][cl] = v;
    }
    __syncthreads();
    // mini-Cholesky on the panel (conflict-free buffer; pivots >= 1, no pivoting)
    for (int jl = 0; jl < kb; ++jl){
      float d = Pn[jl][jl];
      float inv = 1.0f / sqrtf(d);
      __syncthreads();                     // all read d before the column is scaled
      for (int i = jl + tid; i < rows; i += 256) Pn[i][jl] *= inv;
      __syncthreads();
      for (int i = jl + 1 + tid; i < rows; i += 256){
        float pij = Pn[i][jl];
        for (int cl = jl + 1; cl < kb; ++cl) Pn[i][cl] -= pij * Pn[cl][jl];
      }
      __syncthreads();
    }
    // invert the kb x kb lower-tri diagonal block; write INVERSE into Lp diag slots
    if (tid < kb){
      int j = tid;
      float x[NB];
      x[j] = 1.0f / Pn[j][j];
      for (int i = j + 1; i < kb; ++i){
        float s = 0.f;
        for (int k = j; k < i; ++k) s += Pn[i][k] * x[k];
        x[i] = -s / Pn[i][i];
      }
      for (int i = j; i < kb; ++i) Lp[offr(k0+i) + k0 + j] = x[i];
    }
    // write back off-diagonal panel rows (final L values)
    for (int e = tid; e < (rows - kb)*NB; e += 256){
      int r = kb + (e >> 4), cl = e & 15;
      if (cl < kb) Lp[offr(k0+r) + k0 + cl] = Pn[r][cl];
    }
    // trailing SYRK update: Lp[i][j] -= sum_k Pn[i][k]*Pn[j][k], 4x4 register tiles
    const int rs = rows - kb;            // if kb<NB then rs==0
    if (rs > 0){
      const int nt4 = (rs + 3) >> 2;
      const int ntile = (nt4*(nt4+1)) >> 1;
      for (int e = tid; e < ntile; e += 256){
        int ti = row_of(e);
        int tj = e - offr(ti);
        int i0 = kb + 4*ti, j0 = kb + 4*tj;
        float acc[4][4] = {};
        #pragma unroll 4
        for (int k = 0; k < NB; ++k){
          float a0 = Pn[i0][k], a1 = Pn[i0+1][k], a2 = Pn[i0+2][k], a3 = Pn[i0+3][k];
          float b0 = Pn[j0][k], b1 = Pn[j0+1][k], b2 = Pn[j0+2][k], b3 = Pn[j0+3][k];
          acc[0][0] += a0*b0; acc[0][1] += a0*b1; acc[0][2] += a0*b2; acc[0][3] += a0*b3;
          acc[1][0] += a1*b0; acc[1][1] += a1*b1; acc[1][2] += a1*b2; acc[1][3] += a1*b3;
          acc[2][0] += a2*b0; acc[2][1] += a2*b1; acc[2][2] += a2*b2; acc[2][3] += a2*b3;
          acc[3][0] += a3*b0; acc[3][1] += a3*b1; acc[3][2] += a3*b2; acc[3][3] += a3*b3;
        }
        #pragma unroll
        for (int u = 0; u < 4; ++u){
          int gi = k0 + i0 + u;
          if (gi < m){
            int og = offr(gi);
            #pragma unroll
            for (int v2 = 0; v2 < 4; ++v2){
              int gj = k0 + j0 + v2;
              if (gj <= gi) Lp[og + gj] -= acc[u][v2];
            }
          }
        }
      }
    }
    __syncthreads();
  }

  // ---- store packed L (with inverted diag blocks) ----
  float* Wg = ws + OFF_W + (size_t)blk * PACK;
  for (int e = tid; e < tot; e += 256) Wg[e] = Lp[e];
}

// ---------------- apply: blocked TRSM forward solve, quad = ||d||^2 - ||L^-1 e||^2 ----------------
__global__ __launch_bounds__(256) void k_apply(float* ws){
  __shared__ float E[MMAX][64];   // e, progressively overwritten with z; 61.4 KB
  __shared__ float R[NB][64];     // acc publish buffer / final reduce; 4 KB
  const int p = blockIdx.z, c = blockIdx.y, q0 = blockIdx.x*64;
  const int tid = threadIdx.x;
  const int* wsI = (const int*)(ws + OFF_INT);
  const int n = wsI[c], m = T + n;
  const int nt = (m + NB - 1)/NB;
  const int* idxc = wsI + C + c*MAXN;
  const float* cf = ws + OFF_CLSF + c*8;
  const float sqs = cf[5], sqa = cf[6];
  const float gmcv = ws[OFF_GMC + p*C + c];
  const float mmv  = ws[OFF_MM  + p*C + c];
  const float* Gmp = ws + OFF_GM + (size_t)p*T*C;
  const float* SQp = ws + OFF_SQ + (size_t)p*T*NQ;
  const float* gqp = ws + OFF_GQ + p*NQ + q0;
  const float* qnp = ws + OFF_QN + p*NQ + q0;
  const float* mqp = ws + OFF_MQ + ((size_t)(p*C + c))*NQ + q0;
  const float* Wb  = ws + OFF_W + (size_t)(p*C + c)*PACK;

  for (int lin = tid; lin < m*64; lin += 256){
    int j = lin >> 6, ql = lin & 63;
    float v;
    if (j < T){
      v = sqs*(Gmp[j*C + c] - SQp[j*NQ + q0 + ql] - gmcv + gqp[ql]);
    } else {
      int u = idxc[j - T];
      v = sqa*(Gmp[u*C + c] - SQp[u*NQ + q0 + ql] - mmv + mqp[ql]);
    }
    E[j][ql] = v;
  }
  __syncthreads();

  const int rw = tid >> 4;            // 0..15: row within 16-block
  const int q4 = (tid & 15) * 4;      // 4 consecutive queries
  float ss0 = 0.f, ss1 = 0.f, ss2 = 0.f, ss3 = 0.f;

  for (int b = 0; b < nt; ++b){
    const int k0 = b*NB;
    const int r = k0 + rw;
    const bool act = (r < m);
    const float* wr = Wb + (act ? offr(r) : 0);
    float a0, a1, a2, a3;
    if (act){
      const float4 e0 = *(const float4*)&E[r][q4];
      a0 = e0.x; a1 = e0.y; a2 = e0.z; a3 = e0.w;
      #pragma unroll 4
      for (int k = 0; k < k0; ++k){
        float lv = wr[k];
        const float4 ev = *(const float4*)&E[k][q4];
        a0 -= lv*ev.x; a1 -= lv*ev.y; a2 -= lv*ev.z; a3 -= lv*ev.w;
      }
      float4 st = {a0, a1, a2, a3};
      *(float4*)&R[rw][q4] = st;
    }
    __syncthreads();
    if (act){
      float z0 = 0.f, z1 = 0.f, z2 = 0.f, z3 = 0.f;
      for (int j = 0; j <= rw; ++j){
        float dv = wr[k0 + j];        // inverted diag block, packed in place
        const float4 rv = *(const float4*)&R[j][q4];
        z0 += dv*rv.x; z1 += dv*rv.y; z2 += dv*rv.z; z3 += dv*rv.w;
      }
      ss0 += z0*z0; ss1 += z1*z1; ss2 += z2*z2; ss3 += z3*z3;
      float4 st = {z0, z1, z2, z3};
      *(float4*)&E[r][q4] = st;       // own row; nobody reads it this phase
    }
    __syncthreads();
  }

  // reduce ||z||^2 over the 16 row-groups per query
  float4 st = {ss0, ss1, ss2, ss3};
  *(float4*)&R[rw][q4] = st;
  __syncthreads();
  if (tid < 64){
    int q = tid;
    float tt = 0.f;
    #pragma unroll
    for (int j = 0; j < NB; ++j) tt += R[j][q];
    float quad = mmv - 2.f*mqp[q] + qnp[q] - tt;
    ws[OFF_QUAD + ((size_t)p*NQ + q0 + q)*C + c] = quad;
  }
}

// ---------------- logits: mean over p ----------------
__global__ void k_logits(const float* ws, float* out){
  int lin = blockIdx.x*256 + threadIdx.x;
  if (lin < QL){
    float s = 0.f;
    for (int p = 0; p < P; ++p) s += ws[OFF_QUAD + (size_t)p*NQ*C + lin];
    out[lin] = -s * (1.0f/P);
  }
}

extern "C" void kernel_launch(void* const* d_in, const int* in_sizes, int n_in,
                              void* d_out, int out_size, void* d_ws, size_t ws_size,
                              hipStream_t stream){
  const float* X   = (const float*)d_in[0];
  const int*   lab = (const int*)d_in[1];
  const float* Qf  = (const float*)d_in[2];
  float* out = (float*)d_out;
  float* ws  = (float*)d_ws;

  k_setup <<<1, 64, 0, stream>>>(lab, ws);
  k_gram  <<<dim3(7,7,P),  dim3(16,16), 0, stream>>>(X, ws);
  k_pstats<<<P, 256, 0, stream>>>(ws);
  k_means <<<P*C, 256, 0, stream>>>(X, ws, out);
  k_sq    <<<dim3(7,16,P), dim3(16,16), 0, stream>>>(X, Qf, ws);
  k_qstats<<<dim3(4,P), 256, 0, stream>>>(Qf, ws);
  k_factor<<<P*C, 256, 0, stream>>>(ws);
  k_apply <<<dim3(16,C,P), 256, 0, stream>>>(ws);
  k_logits<<<QL/256, 256, 0, stream>>>(ws, out);
}